// Round 2
// baseline (277.154 us; speedup 1.0000x reference)
//
#include <hip/hip_runtime.h>

static constexpr float kIouT = 0.35f;
static constexpr float kScoreT = 0.5f;

// Bit-exact mirror of the reference IoU (no FMA contraction).
__device__ __forceinline__ float iou_f(const float4 a, const float4 b) {
  float areaA = __fmul_rn(a.z - a.x, a.w - a.y);
  float areaB = __fmul_rn(b.z - b.x, b.w - b.y);
  float iy1 = fmaxf(a.x, b.x);
  float ix1 = fmaxf(a.y, b.y);
  float iy2 = fminf(a.z, b.z);
  float ix2 = fminf(a.w, b.w);
  float dy = fmaxf(iy2 - iy1, 0.0f);
  float dx = fmaxf(ix2 - ix1, 0.0f);
  float inter = __fmul_rn(dy, dx);
  float uni = (areaA + areaB) - inter;
  return (uni > 0.0f) ? __fdiv_rn(inter, uni) : 0.0f;
}

// ---------------- kernel 1 — per-image bitonic sort ----------------
// key = (~score_bits << 32) | idx, ascending == stable argsort(-scores).
__global__ __launch_bounds__(1024)
void nms_sort_kernel(const float* __restrict__ scores,
                     const float4* __restrict__ boxes,
                     unsigned long long* __restrict__ skeys,
                     float4* __restrict__ sboxes,
                     int* __restrict__ Mcnt, int N) {
  extern __shared__ unsigned long long keys[];
  __shared__ int s_m;
  const int img = blockIdx.x;
  const int tid = threadIdx.x;
  const float* sc = scores + (size_t)img * N;
  const float4* bx = boxes + (size_t)img * N;
  if (tid == 0) s_m = 0;
  __syncthreads();
  int cnt = 0;
  for (int i = tid; i < N; i += blockDim.x) {
    float s = sc[i];
    keys[i] = ((unsigned long long)(~__float_as_uint(s)) << 32) | (unsigned)i;
    if (s > kScoreT) cnt++;
  }
  if (cnt) atomicAdd(&s_m, cnt);
  __syncthreads();
  for (int k = 2; k <= N; k <<= 1) {
    for (int j = k >> 1; j > 0; j >>= 1) {
      for (int i = tid; i < N; i += blockDim.x) {
        int ixj = i ^ j;
        if (ixj > i) {
          unsigned long long a = keys[i];
          unsigned long long b = keys[ixj];
          bool up = ((i & k) == 0);
          if (up ? (a > b) : (a < b)) { keys[i] = b; keys[ixj] = a; }
        }
      }
      __syncthreads();
    }
  }
  for (int i = tid; i < N; i += blockDim.x) {
    unsigned long long ki = keys[i];
    skeys[(size_t)img * N + i] = ki;
    sboxes[(size_t)img * N + i] = bx[(unsigned)ki];
  }
  if (tid == 0) Mcnt[img] = s_m;
}

// ------------- kernel 2 — pairwise IoU suppression masks -----------
__global__ __launch_bounds__(256)
void nms_mask_kernel(const float4* __restrict__ sboxes,
                     const int* __restrict__ Mcnt,
                     unsigned long long* __restrict__ mask,
                     int N, int totalRows) {
  const int wid = (int)(((unsigned)blockIdx.x * blockDim.x + threadIdx.x) >> 6);
  const int lane = threadIdx.x & 63;
  if (wid >= totalRows) return;
  const int img = wid / N;
  const int row = wid - img * N;
  const int m = Mcnt[img];
  if (row >= m) return;
  const float4* sb = sboxes + (size_t)img * N;
  const float4 bi = sb[row];
  const int nw = (m + 63) >> 6;
  unsigned long long* mrow = mask + (size_t)wid * (size_t)(N >> 6);
  for (int w = row >> 6; w < nw; ++w) {
    int j = (w << 6) | lane;
    bool sup = false;
    if (j > row && j < m) sup = iou_f(bi, sb[j]) > kIouT;
    unsigned long long bm = __ballot(sup);
    if (lane == 0) mrow[w] = bm;
  }
}

// ------------- kernel 3 — single-wave scan, chunked LDS prefetch ----
// Candidates visited in increasing order -> chunk them in groups of 64.
// While scanning chunk c from LDS, chunk c+1's 64 mask rows are in flight
// as 64 independent global loads held in a fully-unrolled register array
// (static indices -> VGPRs, no scratch), committed to LDS at the boundary.
// Per-keep chain: ds_read_b64 (~120cy) -> OR -> shfl, vs ~1900cy before.
__device__ __forceinline__ void write_row(float* o, int kept,
                                          const unsigned long long* kg,
                                          const float4* sb, const float* an,
                                          int i) {
  const unsigned long long ki = kg[i];
  const float4 bi = sb[i];
  const unsigned idx = (unsigned)ki;
  float* row = o + kept * 7;
  row[0] = __uint_as_float(~(unsigned)(ki >> 32));
  row[1] = bi.x; row[2] = bi.y; row[3] = bi.z; row[4] = bi.w;
  row[5] = an[idx * 4 + 2];
  row[6] = an[idx * 4 + 3];
}

__global__ __launch_bounds__(64)
void nms_scan_kernel(const unsigned long long* __restrict__ skeys,
                     const float4* __restrict__ sboxes,
                     const int* __restrict__ Mcnt,
                     const unsigned long long* __restrict__ mask,
                     const float* __restrict__ anchors,
                     float* __restrict__ out, int N, int NS, int capnw) {
  extern __shared__ unsigned long long lbuf[];  // [2][64][nw]
  const int img = blockIdx.x;
  const int lane = threadIdx.x;
  const int m = Mcnt[img];
  const int nw = (m + 63) >> 6;
  const int stride = N >> 6;  // mask row stride in u64 words
  const unsigned long long* kg = skeys + (size_t)img * N;
  const float4* sb = sboxes + (size_t)img * N;
  const float* an = anchors + (size_t)img * (size_t)N * 4;
  float* o = out + (size_t)img * NS * 7;
  const unsigned long long* mbase = mask + (size_t)img * (size_t)N * stride;
  unsigned long long remv = 0ull;
  int kept = 0;

  if (m > 0 && nw <= capnw) {
    unsigned long long pref[64];  // chunk of 64 mask rows, word `lane` each
    auto issue = [&](int cb) {    // cb multiple of 64, cb < m (rows < N safe)
      const unsigned long long* p = mbase + (size_t)cb * stride + lane;
#pragma unroll
      for (int r = 0; r < 64; ++r) pref[r] = p[(size_t)r * stride];
    };
    auto commit = [&](int buf) {
      if (lane < nw) {
        unsigned long long* dst = lbuf + (size_t)buf * 64 * nw + lane;
#pragma unroll
        for (int r = 0; r < 64; ++r) dst[r * nw] = pref[r];
      }
    };
    issue(0);
    commit(0);
    if (64 < m) issue(64);
    int cur = 0;
    for (int i = 0; i < m && kept < NS; ++i) {
      const int c = i >> 6;
      if (c != cur) {               // entering chunk c (== cur+1)
        commit(c & 1);              // chunk c was prefetched -> LDS
        const int nb = (c + 1) << 6;
        if (nb < m) issue(nb);      // launch prefetch of chunk c+1
        cur = c;
      }
      const unsigned long long rw = __shfl(remv, c, 64);
      if ((rw >> (i & 63)) & 1ull) continue;
      if (lane == 0) write_row(o, kept, kg, sb, an, i);
      kept++;
      if (kept >= NS) break;
      if (lane >= c && lane < nw)
        remv |= lbuf[(size_t)(c & 1) * 64 * nw + (i & 63) * nw + lane];
    }
  } else if (m > 0) {
    // safety fallback: per-keep global mask-row load (round-0 logic)
    for (int i = 0; i < m && kept < NS; ++i) {
      const unsigned long long rw = __shfl(remv, i >> 6, 64);
      if ((rw >> (i & 63)) & 1ull) continue;
      if (lane == 0) write_row(o, kept, kg, sb, an, i);
      kept++;
      const unsigned long long* mrow = mbase + (size_t)i * stride;
      if (lane >= (i >> 6) && lane < nw) remv |= mrow[lane];
    }
  }
  // zero unfilled tail (rows disjoint from filled ones)
  for (int t = kept * 7 + lane; t < NS * 7; t += 64) o[t] = 0.0f;
}

// --------------- fallback: fused sort + on-the-fly scan (no d_ws) -------------
__global__ __launch_bounds__(1024)
void nms_fused_kernel(const float* __restrict__ scores,
                      const float4* __restrict__ boxes,
                      const float* __restrict__ anchors,
                      float* __restrict__ out, int N, int NS) {
  __shared__ unsigned long long keys[4096];
  __shared__ int s_m;
  if (N > 4096) return;
  const int img = blockIdx.x;
  const int tid = threadIdx.x;
  const float* sc = scores + (size_t)img * N;
  const float4* bx = boxes + (size_t)img * N;
  if (tid == 0) s_m = 0;
  __syncthreads();
  int cnt = 0;
  for (int i = tid; i < N; i += blockDim.x) {
    float s = sc[i];
    keys[i] = ((unsigned long long)(~__float_as_uint(s)) << 32) | (unsigned)i;
    if (s > kScoreT) cnt++;
  }
  if (cnt) atomicAdd(&s_m, cnt);
  __syncthreads();
  for (int k = 2; k <= N; k <<= 1) {
    for (int j = k >> 1; j > 0; j >>= 1) {
      for (int i = tid; i < N; i += blockDim.x) {
        int ixj = i ^ j;
        if (ixj > i) {
          unsigned long long a = keys[i];
          unsigned long long b = keys[ixj];
          bool up = ((i & k) == 0);
          if (up ? (a > b) : (a < b)) { keys[i] = b; keys[ixj] = a; }
        }
      }
      __syncthreads();
    }
  }
  if (tid >= 64) return;
  const int lane = tid;
  const int m = s_m;
  const int nw = (m + 63) >> 6;
  const float* an = anchors + (size_t)img * N * 4;
  float* o = out + (size_t)img * NS * 7;
  unsigned long long remv = 0ull;
  int kept = 0;
  for (int i = 0; i < m && kept < NS; ++i) {
    unsigned long long rw = __shfl(remv, i >> 6, 64);
    if ((rw >> (i & 63)) & 1ull) continue;
    unsigned long long ki = keys[i];
    float4 bi = bx[(unsigned)ki];
    if (lane == 0) {
      unsigned idx = (unsigned)ki;
      float* row = o + kept * 7;
      row[0] = __uint_as_float(~(unsigned)(ki >> 32));
      row[1] = bi.x; row[2] = bi.y; row[3] = bi.z; row[4] = bi.w;
      row[5] = an[idx * 4 + 2];
      row[6] = an[idx * 4 + 3];
    }
    kept++;
    for (int w2 = i >> 6; w2 < nw; ++w2) {
      int j = (w2 << 6) | lane;
      bool sup = false;
      if (j > i && j < m) sup = iou_f(bi, bx[(unsigned)keys[j]]) > kIouT;
      unsigned long long bm = __ballot(sup);
      if (lane == w2) remv |= bm;
    }
  }
  for (int t = kept * 7 + lane; t < NS * 7; t += 64) o[t] = 0.0f;
}

extern "C" void kernel_launch(void* const* d_in, const int* in_sizes, int n_in,
                              void* d_out, int out_size, void* d_ws, size_t ws_size,
                              hipStream_t stream) {
  const float* scores = (const float*)d_in[0];
  const float4* boxes = (const float4*)d_in[1];
  const float* anchors = (const float*)d_in[2];
  float* out = (float*)d_out;
  const int B = 8;
  const int N = in_sizes[0] / B;      // 4096 boxes/image
  const int NS = out_size / (B * 7);  // 300 samples

  const size_t nTot = (size_t)B * (size_t)N;
  const size_t keysB = nTot * 8;
  const size_t sboxB = nTot * 16;
  const size_t mcntB = 256;
  const size_t maskB = nTot * (size_t)(N >> 6) * 8;
  const size_t need = keysB + sboxB + mcntB + maskB;

  if (ws_size >= need && (N & (N - 1)) == 0 && N >= 64) {
    char* p = (char*)d_ws;
    unsigned long long* skeys = (unsigned long long*)p; p += keysB;
    float4* sboxes = (float4*)p;                         p += sboxB;
    int* Mcnt = (int*)p;                                 p += mcntB;
    unsigned long long* mask = (unsigned long long*)p;

    nms_sort_kernel<<<B, 1024, (size_t)N * 8, stream>>>(scores, boxes, skeys,
                                                        sboxes, Mcnt, N);
    const int totalRows = B * N;
    const int blocks = (int)(((long long)totalRows * 64 + 255) / 256);
    nms_mask_kernel<<<blocks, 256, 0, stream>>>(sboxes, Mcnt, mask, N, totalRows);
    const int stride = N >> 6;
    const int capnw = stride < 48 ? stride : 48;     // 2*64*48*8 = 48 KiB LDS
    const size_t shmem = (size_t)2 * 64 * capnw * 8;
    nms_scan_kernel<<<B, 64, shmem, stream>>>(skeys, sboxes, Mcnt, mask,
                                              anchors, out, N, NS, capnw);
  } else {
    nms_fused_kernel<<<B, 1024, 0, stream>>>(scores, boxes, anchors, out, N, NS);
  }
}

// Round 3
// 152.535 us; speedup vs baseline: 1.8170x; 1.8170x over previous
//
#include <hip/hip_runtime.h>

static constexpr float kIouT = 0.35f;
static constexpr float kScoreT = 0.5f;
static constexpr int kMaxNW = 48;   // scan LDS tile supports m <= 48*64 = 3072
static constexpr int kMaxKeep = 512;

// Bit-exact mirror of the reference IoU (no FMA contraction).
__device__ __forceinline__ float iou_f(const float4 a, const float4 b) {
  float areaA = __fmul_rn(a.z - a.x, a.w - a.y);
  float areaB = __fmul_rn(b.z - b.x, b.w - b.y);
  float iy1 = fmaxf(a.x, b.x);
  float ix1 = fmaxf(a.y, b.y);
  float iy2 = fminf(a.z, b.z);
  float ix2 = fminf(a.w, b.w);
  float dy = fmaxf(iy2 - iy1, 0.0f);
  float dx = fmaxf(ix2 - ix1, 0.0f);
  float inter = __fmul_rn(dy, dx);
  float uni = (areaA + areaB) - inter;
  return (uni > 0.0f) ? __fdiv_rn(inter, uni) : 0.0f;
}

// ---------------- kernel 1 — per-image bitonic sort ----------------
// key = (~score_bits << 32) | idx, ascending == stable argsort(-scores).
__global__ __launch_bounds__(1024)
void nms_sort_kernel(const float* __restrict__ scores,
                     const float4* __restrict__ boxes,
                     unsigned long long* __restrict__ skeys,
                     float4* __restrict__ sboxes,
                     int* __restrict__ Mcnt, int N) {
  extern __shared__ unsigned long long keys[];
  __shared__ int s_m;
  const int img = blockIdx.x;
  const int tid = threadIdx.x;
  const float* sc = scores + (size_t)img * N;
  const float4* bx = boxes + (size_t)img * N;
  if (tid == 0) s_m = 0;
  __syncthreads();
  int cnt = 0;
  for (int i = tid; i < N; i += blockDim.x) {
    float s = sc[i];
    keys[i] = ((unsigned long long)(~__float_as_uint(s)) << 32) | (unsigned)i;
    if (s > kScoreT) cnt++;
  }
  if (cnt) atomicAdd(&s_m, cnt);
  __syncthreads();
  for (int k = 2; k <= N; k <<= 1) {
    for (int j = k >> 1; j > 0; j >>= 1) {
      for (int i = tid; i < N; i += blockDim.x) {
        int ixj = i ^ j;
        if (ixj > i) {
          unsigned long long a = keys[i];
          unsigned long long b = keys[ixj];
          bool up = ((i & k) == 0);
          if (up ? (a > b) : (a < b)) { keys[i] = b; keys[ixj] = a; }
        }
      }
      __syncthreads();
    }
  }
  for (int i = tid; i < N; i += blockDim.x) {
    unsigned long long ki = keys[i];
    skeys[(size_t)img * N + i] = ki;
    sboxes[(size_t)img * N + i] = bx[(unsigned)ki];
  }
  if (tid == 0) Mcnt[img] = s_m;
}

// ------------- kernel 2 — pairwise IoU suppression masks -----------
__global__ __launch_bounds__(256)
void nms_mask_kernel(const float4* __restrict__ sboxes,
                     const int* __restrict__ Mcnt,
                     unsigned long long* __restrict__ mask,
                     int N, int totalRows) {
  const int wid = (int)(((unsigned)blockIdx.x * blockDim.x + threadIdx.x) >> 6);
  const int lane = threadIdx.x & 63;
  if (wid >= totalRows) return;
  const int img = wid / N;
  const int row = wid - img * N;
  const int m = Mcnt[img];
  if (row >= m) return;
  const float4* sb = sboxes + (size_t)img * N;
  const float4 bi = sb[row];
  const int nw = (m + 63) >> 6;
  unsigned long long* mrow = mask + (size_t)wid * (size_t)(N >> 6);
  for (int w = row >> 6; w < nw; ++w) {
    int j = (w << 6) | lane;
    bool sup = false;
    if (j > row && j < m) sup = iou_f(bi, sb[j]) > kIouT;
    unsigned long long bm = __ballot(sup);
    if (lane == 0) mrow[w] = bm;
  }
}

// ------------- kernel 3 — 2-wave scan: producer wave + bit-scan wave ----------
// Wave 1 streams chunk c+1's mask rows into double-buffered LDS while wave 0
// scans chunk c. Wave 0 keeps word c locally (one shfl per CHUNK), walks
// candidate bits with ctz (skips ~free), per keep: LDS broadcast read of
// row[c] + per-lane read of row[lane]. Kept indices recorded in LDS; output
// rows written afterwards by all 128 threads in parallel (no serial lane-0
// dependent global loads on the scan chain).
__global__ __launch_bounds__(128)
void nms_scan_kernel(const unsigned long long* __restrict__ skeys,
                     const float4* __restrict__ sboxes,
                     const int* __restrict__ Mcnt,
                     const unsigned long long* __restrict__ mask,
                     const float* __restrict__ anchors,
                     float* __restrict__ out, int N, int NS) {
  __shared__ unsigned long long lbuf[2 * 64 * kMaxNW];  // 48 KiB
  __shared__ int keptlist[kMaxKeep];
  __shared__ int s_done, s_kept;
  const int img = blockIdx.x;
  const int tid = threadIdx.x;
  const int lane = tid & 63;
  const int wv = tid >> 6;
  const int m = Mcnt[img];
  const int nw = (m + 63) >> 6;
  const int stride = N >> 6;  // mask row stride in u64
  const unsigned long long* mbase = mask + (size_t)img * (size_t)N * stride;
  const unsigned long long* kg = skeys + (size_t)img * N;
  const float4* sb = sboxes + (size_t)img * N;
  const float* an = anchors + (size_t)img * (size_t)N * 4;
  float* o = out + (size_t)img * NS * 7;
  if (tid == 0) { s_done = 0; s_kept = 0; }

  int kept = 0;
  unsigned long long remv = 0ull;

  if (m > 0 && nw <= kMaxNW) {
    const int nch = nw;
    // prologue: wave 1 loads chunk 0 into buf 0
    if (wv == 1) {
      const int w = 0 + lane;  // chunk 0 valid words start at 0
      if (w < nw) {
        const int rlim = (m < 64) ? m : 64;
        const unsigned long long* g = mbase + w;
        unsigned long long* dst = lbuf + w;
        for (int r = 0; r < rlim; ++r)
          dst[(size_t)r * kMaxNW] = g[(size_t)r * stride];
      }
    }
    __syncthreads();
    for (int c = 0; c < nch; ++c) {
      if (wv == 0) {
        // ---- scan chunk c from buf (c&1) ----
        unsigned long long local = __shfl(remv, c, 64);
        const int rem = m - (c << 6);
        const int lim = rem < 64 ? rem : 64;
        unsigned long long avail = ~local;
        if (lim < 64) avail &= ((1ull << lim) - 1ull);
        const unsigned long long* buf = lbuf + (size_t)(c & 1) * 64 * kMaxNW;
        while (avail != 0ull && kept < NS) {
          const int b = __builtin_ctzll(avail);
          const int i = (c << 6) + b;
          if (lane == 0) keptlist[kept] = i;
          kept++;
          const unsigned long long* row = buf + (size_t)b * kMaxNW;
          const unsigned long long rc = row[c];                       // broadcast
          const unsigned long long rl =
              (lane > c && lane < nw) ? row[lane] : 0ull;             // per-lane
          local |= rc;
          remv |= rl;
          avail &= ~(1ull << b);
          avail &= ~local;
        }
        if (lane == 0 && kept >= NS) s_done = 1;
      } else if (c + 1 < nch) {
        // ---- load chunk c+1 into buf ((c+1)&1) ----
        const int cc = c + 1;
        const int w = cc + lane;  // valid words of rows in chunk cc start at cc
        if (w < nw) {
          const int base = cc << 6;
          int rlim = m - base;
          if (rlim > 64) rlim = 64;
          const unsigned long long* g = mbase + (size_t)base * stride + w;
          unsigned long long* dst =
              lbuf + (size_t)(cc & 1) * 64 * kMaxNW + w;
          for (int r = 0; r < rlim; ++r)
            dst[(size_t)r * kMaxNW] = g[(size_t)r * stride];
        }
      }
      __syncthreads();
      if (s_done) break;
    }
  } else if (m > 0) {
    // safety fallback (m > 3072): wave 0 only, per-keep global mask-row loads.
    if (wv == 0) {
      for (int i = 0; i < m && kept < NS; ++i) {
        const unsigned long long rw = __shfl(remv, i >> 6, 64);
        if ((rw >> (i & 63)) & 1ull) continue;
        if (lane == 0) keptlist[kept] = i;
        kept++;
        const unsigned long long* mrow = mbase + (size_t)i * stride;
        if (lane >= (i >> 6) && lane < nw) remv |= mrow[lane];
      }
    }
  }

  if (wv == 0 && lane == 0) s_kept = kept;
  __syncthreads();
  const int K = s_kept;
  // parallel output: 128 threads over K kept rows
  for (int t = tid; t < K; t += 128) {
    const int i = keptlist[t];
    const unsigned long long ki = kg[i];
    const float4 bi = sb[i];
    const unsigned idx = (unsigned)ki;
    float* row = o + t * 7;
    row[0] = __uint_as_float(~(unsigned)(ki >> 32));
    row[1] = bi.x; row[2] = bi.y; row[3] = bi.z; row[4] = bi.w;
    row[5] = an[idx * 4 + 2];
    row[6] = an[idx * 4 + 3];
  }
  for (int t = K * 7 + tid; t < NS * 7; t += 128) o[t] = 0.0f;
}

// --------------- fallback: fused sort + on-the-fly scan (no d_ws) -------------
__global__ __launch_bounds__(1024)
void nms_fused_kernel(const float* __restrict__ scores,
                      const float4* __restrict__ boxes,
                      const float* __restrict__ anchors,
                      float* __restrict__ out, int N, int NS) {
  __shared__ unsigned long long keys[4096];
  __shared__ int s_m;
  if (N > 4096) return;
  const int img = blockIdx.x;
  const int tid = threadIdx.x;
  const float* sc = scores + (size_t)img * N;
  const float4* bx = boxes + (size_t)img * N;
  if (tid == 0) s_m = 0;
  __syncthreads();
  int cnt = 0;
  for (int i = tid; i < N; i += blockDim.x) {
    float s = sc[i];
    keys[i] = ((unsigned long long)(~__float_as_uint(s)) << 32) | (unsigned)i;
    if (s > kScoreT) cnt++;
  }
  if (cnt) atomicAdd(&s_m, cnt);
  __syncthreads();
  for (int k = 2; k <= N; k <<= 1) {
    for (int j = k >> 1; j > 0; j >>= 1) {
      for (int i = tid; i < N; i += blockDim.x) {
        int ixj = i ^ j;
        if (ixj > i) {
          unsigned long long a = keys[i];
          unsigned long long b = keys[ixj];
          bool up = ((i & k) == 0);
          if (up ? (a > b) : (a < b)) { keys[i] = b; keys[ixj] = a; }
        }
      }
      __syncthreads();
    }
  }
  if (tid >= 64) return;
  const int lane = tid;
  const int m = s_m;
  const int nw = (m + 63) >> 6;
  const float* an = anchors + (size_t)img * N * 4;
  float* o = out + (size_t)img * NS * 7;
  unsigned long long remv = 0ull;
  int kept = 0;
  for (int i = 0; i < m && kept < NS; ++i) {
    unsigned long long rw = __shfl(remv, i >> 6, 64);
    if ((rw >> (i & 63)) & 1ull) continue;
    unsigned long long ki = keys[i];
    float4 bi = bx[(unsigned)ki];
    if (lane == 0) {
      unsigned idx = (unsigned)ki;
      float* row = o + kept * 7;
      row[0] = __uint_as_float(~(unsigned)(ki >> 32));
      row[1] = bi.x; row[2] = bi.y; row[3] = bi.z; row[4] = bi.w;
      row[5] = an[idx * 4 + 2];
      row[6] = an[idx * 4 + 3];
    }
    kept++;
    for (int w2 = i >> 6; w2 < nw; ++w2) {
      int j = (w2 << 6) | lane;
      bool sup = false;
      if (j > i && j < m) sup = iou_f(bi, bx[(unsigned)keys[j]]) > kIouT;
      unsigned long long bm = __ballot(sup);
      if (lane == w2) remv |= bm;
    }
  }
  for (int t = kept * 7 + lane; t < NS * 7; t += 64) o[t] = 0.0f;
}

extern "C" void kernel_launch(void* const* d_in, const int* in_sizes, int n_in,
                              void* d_out, int out_size, void* d_ws, size_t ws_size,
                              hipStream_t stream) {
  const float* scores = (const float*)d_in[0];
  const float4* boxes = (const float4*)d_in[1];
  const float* anchors = (const float*)d_in[2];
  float* out = (float*)d_out;
  const int B = 8;
  const int N = in_sizes[0] / B;      // 4096 boxes/image
  const int NS = out_size / (B * 7);  // 300 samples

  const size_t nTot = (size_t)B * (size_t)N;
  const size_t keysB = nTot * 8;
  const size_t sboxB = nTot * 16;
  const size_t mcntB = 256;
  const size_t maskB = nTot * (size_t)(N >> 6) * 8;
  const size_t need = keysB + sboxB + mcntB + maskB;

  if (ws_size >= need && (N & (N - 1)) == 0 && N >= 64 && NS <= kMaxKeep) {
    char* p = (char*)d_ws;
    unsigned long long* skeys = (unsigned long long*)p; p += keysB;
    float4* sboxes = (float4*)p;                         p += sboxB;
    int* Mcnt = (int*)p;                                 p += mcntB;
    unsigned long long* mask = (unsigned long long*)p;

    nms_sort_kernel<<<B, 1024, (size_t)N * 8, stream>>>(scores, boxes, skeys,
                                                        sboxes, Mcnt, N);
    const int totalRows = B * N;
    const int blocks = (int)(((long long)totalRows * 64 + 255) / 256);
    nms_mask_kernel<<<blocks, 256, 0, stream>>>(sboxes, Mcnt, mask, N, totalRows);
    nms_scan_kernel<<<B, 128, 0, stream>>>(skeys, sboxes, Mcnt, mask, anchors,
                                           out, N, NS);
  } else {
    nms_fused_kernel<<<B, 1024, 0, stream>>>(scores, boxes, anchors, out, N, NS);
  }
}

// Round 4
// 114.441 us; speedup vs baseline: 2.4218x; 1.3329x over previous
//
#include <hip/hip_runtime.h>

static constexpr float kIouT = 0.35f;
static constexpr float kScoreT = 0.5f;
static constexpr int kMaxNW = 48;    // scan LDS tile supports m <= 48*64 = 3072
static constexpr int kStride = 49;   // padded LDS row stride (bank-conflict fix)
static constexpr int kMaxKeep = 512;

// Bit-exact mirror of the reference IoU (no FMA contraction).
__device__ __forceinline__ float iou_f(const float4 a, const float4 b) {
  float areaA = __fmul_rn(a.z - a.x, a.w - a.y);
  float areaB = __fmul_rn(b.z - b.x, b.w - b.y);
  float iy1 = fmaxf(a.x, b.x);
  float ix1 = fmaxf(a.y, b.y);
  float iy2 = fminf(a.z, b.z);
  float ix2 = fminf(a.w, b.w);
  float dy = fmaxf(iy2 - iy1, 0.0f);
  float dx = fmaxf(ix2 - ix1, 0.0f);
  float inter = __fmul_rn(dy, dx);
  float uni = (areaA + areaB) - inter;
  return (uni > 0.0f) ? __fdiv_rn(inter, uni) : 0.0f;
}

// ---------------- kernel 0 — per-image valid count (no atomics) ---------------
__global__ __launch_bounds__(256)
void nms_count_kernel(const float* __restrict__ scores, int* __restrict__ Mcnt,
                      int N) {
  __shared__ int part[4];
  const int img = blockIdx.x, tid = threadIdx.x, lane = tid & 63, wv = tid >> 6;
  const float4* sc4 = (const float4*)(scores + (size_t)img * N);
  int c = 0;
  for (int q = tid; q < (N >> 2); q += 256) {
    float4 v = sc4[q];
    c += (v.x > kScoreT) + (v.y > kScoreT) + (v.z > kScoreT) + (v.w > kScoreT);
  }
#pragma unroll
  for (int off = 1; off < 64; off <<= 1) c += __shfl_xor(c, off, 64);
  if (lane == 0) part[wv] = c;
  __syncthreads();
  if (tid == 0) Mcnt[img] = part[0] + part[1] + part[2] + part[3];
}

// ---------------- kernel 1 — rank (counting) sort of the VALID prefix ---------
// One wave per row. For valid row i: rank = #{j: s_j > s_i} + #{j: s_j==s_i,
// j<i}. All invalid j sort strictly after every valid i (s_j <= 0.5 < s_i), so
// counting over ALL j gives the position in the full stable descending sort —
// identical ordering to key=(~score_bits<<32|idx) ascending. Direct scatter:
// skeys[rank], sboxes[rank]. The tail (>= m) is never read downstream.
__global__ __launch_bounds__(256)
void nms_rank_kernel(const float* __restrict__ scores,
                     const float4* __restrict__ boxes,
                     unsigned long long* __restrict__ skeys,
                     float4* __restrict__ sboxes, int N) {
  const int wid = (int)(((unsigned)blockIdx.x * blockDim.x + threadIdx.x) >> 6);
  const int lane = threadIdx.x & 63;
  const int img = wid / N;
  const int row = wid - img * N;
  const float* sc = scores + (size_t)img * N;
  const float si = sc[row];
  if (!(si > kScoreT)) return;
  const float4* sc4 = (const float4*)sc;
  int cnt = 0;
  for (int q = lane; q < (N >> 2); q += 64) {   // coalesced, L1-resident
    const float4 v = sc4[q];
    const int j = q << 2;
    cnt += (v.x > si) + (v.y > si) + (v.z > si) + (v.w > si);
    if (v.x == si && j < row) cnt++;
    if (v.y == si && j + 1 < row) cnt++;
    if (v.z == si && j + 2 < row) cnt++;
    if (v.w == si && j + 3 < row) cnt++;
  }
#pragma unroll
  for (int off = 1; off < 64; off <<= 1) cnt += __shfl_xor(cnt, off, 64);
  if (lane == 0) {
    skeys[(size_t)img * N + cnt] =
        ((unsigned long long)(~__float_as_uint(si)) << 32) | (unsigned)row;
    sboxes[(size_t)img * N + cnt] = boxes[(size_t)img * N + row];
  }
}

// ------------- kernel 2 — pairwise IoU suppression masks -----------
__global__ __launch_bounds__(256)
void nms_mask_kernel(const float4* __restrict__ sboxes,
                     const int* __restrict__ Mcnt,
                     unsigned long long* __restrict__ mask,
                     int N, int totalRows) {
  const int wid = (int)(((unsigned)blockIdx.x * blockDim.x + threadIdx.x) >> 6);
  const int lane = threadIdx.x & 63;
  if (wid >= totalRows) return;
  const int img = wid / N;
  const int row = wid - img * N;
  const int m = Mcnt[img];
  if (row >= m) return;
  const float4* sb = sboxes + (size_t)img * N;
  const float4 bi = sb[row];
  const int nw = (m + 63) >> 6;
  unsigned long long* mrow = mask + (size_t)wid * (size_t)(N >> 6);
  for (int w = row >> 6; w < nw; ++w) {
    int j = (w << 6) | lane;
    bool sup = false;
    if (j > row && j < m) sup = iou_f(bi, sb[j]) > kIouT;
    unsigned long long bm = __ballot(sup);
    if (lane == 0) mrow[w] = bm;
  }
}

// ------------- kernel 3 — 2-wave scan: producer wave + bit-scan wave ----------
// Wave 1 streams chunk c+1's mask rows into double-buffered LDS while wave 0
// scans chunk c. Per-keep critical chain is register-only: diag word preloaded
// per lane at chunk start, rc = shfl(diag, b) (~35cy) instead of an LDS read
// (~120cy). The per-lane remv |= row[lane] OR is off the critical chain.
__global__ __launch_bounds__(128)
void nms_scan_kernel(const unsigned long long* __restrict__ skeys,
                     const float4* __restrict__ sboxes,
                     const int* __restrict__ Mcnt,
                     const unsigned long long* __restrict__ mask,
                     const float* __restrict__ anchors,
                     float* __restrict__ out, int N, int NS) {
  __shared__ unsigned long long lbuf[2 * 64 * kStride];  // ~49 KiB
  __shared__ int keptlist[kMaxKeep];
  __shared__ int s_done, s_kept;
  const int img = blockIdx.x;
  const int tid = threadIdx.x;
  const int lane = tid & 63;
  const int wv = tid >> 6;
  const int m = Mcnt[img];
  const int nw = (m + 63) >> 6;
  const int stride = N >> 6;  // mask row stride in u64
  const unsigned long long* mbase = mask + (size_t)img * (size_t)N * stride;
  const unsigned long long* kg = skeys + (size_t)img * N;
  const float4* sb = sboxes + (size_t)img * N;
  const float* an = anchors + (size_t)img * (size_t)N * 4;
  float* o = out + (size_t)img * NS * 7;
  if (tid == 0) { s_done = 0; s_kept = 0; }

  int kept = 0;
  unsigned long long remv = 0ull;

  if (m > 0 && nw <= kMaxNW) {
    const int nch = nw;
    // prologue: wave 1 loads chunk 0 into buf 0
    if (wv == 1) {
      const int w = lane;
      if (w < nw) {
        const int rlim = (m < 64) ? m : 64;
        const unsigned long long* g = mbase + w;
        unsigned long long* dst = lbuf + w;
        for (int r = 0; r < rlim; ++r)
          dst[(size_t)r * kStride] = g[(size_t)r * stride];
      }
    }
    __syncthreads();
    for (int c = 0; c < nch; ++c) {
      if (wv == 0) {
        // ---- scan chunk c from buf (c&1) ----
        const unsigned long long* buf = lbuf + (size_t)(c & 1) * 64 * kStride;
        const unsigned long long diag = buf[(size_t)lane * kStride + c];
        unsigned long long local = __shfl(remv, c, 64);
        const int rem = m - (c << 6);
        const int lim = rem < 64 ? rem : 64;
        unsigned long long avail = ~local;
        if (lim < 64) avail &= ((1ull << lim) - 1ull);
        while (avail != 0ull && kept < NS) {
          const int b = __builtin_ctzll(avail);
          if (lane == 0) keptlist[kept] = (c << 6) + b;
          kept++;
          const unsigned long long rc = __shfl(diag, b, 64);     // on-chain
          if (lane > c && lane < nw)
            remv |= buf[(size_t)b * kStride + lane];             // off-chain
          local |= rc;
          avail &= ~local;
          avail &= ~(1ull << b);
        }
        if (lane == 0 && kept >= NS) s_done = 1;
      } else if (wv == 1 && c + 1 < nch) {
        // ---- load chunk c+1 into buf ((c+1)&1) ----
        const int cc = c + 1;
        const int w = cc + lane;  // valid words of rows in chunk cc start at cc
        if (w < nw) {
          const int base = cc << 6;
          int rlim = m - base;
          if (rlim > 64) rlim = 64;
          const unsigned long long* g = mbase + (size_t)base * stride + w;
          unsigned long long* dst = lbuf + (size_t)(cc & 1) * 64 * kStride + w;
          for (int r = 0; r < rlim; ++r)
            dst[(size_t)r * kStride] = g[(size_t)r * stride];
        }
      }
      __syncthreads();
      if (s_done) break;
    }
  } else if (m > 0) {
    // safety fallback (m > 3072): wave 0 only, per-keep global mask-row loads.
    if (wv == 0) {
      for (int i = 0; i < m && kept < NS; ++i) {
        const unsigned long long rw = __shfl(remv, i >> 6, 64);
        if ((rw >> (i & 63)) & 1ull) continue;
        if (lane == 0) keptlist[kept] = i;
        kept++;
        const unsigned long long* mrow = mbase + (size_t)i * stride;
        if (lane >= (i >> 6) && lane < nw) remv |= mrow[lane];
      }
    }
  }

  if (wv == 0 && lane == 0) s_kept = kept;
  __syncthreads();
  const int K = s_kept;
  // parallel output: 128 threads over K kept rows
  for (int t = tid; t < K; t += 128) {
    const int i = keptlist[t];
    const unsigned long long ki = kg[i];
    const float4 bi = sb[i];
    const unsigned idx = (unsigned)ki;
    float* row = o + t * 7;
    row[0] = __uint_as_float(~(unsigned)(ki >> 32));
    row[1] = bi.x; row[2] = bi.y; row[3] = bi.z; row[4] = bi.w;
    row[5] = an[idx * 4 + 2];
    row[6] = an[idx * 4 + 3];
  }
  for (int t = K * 7 + tid; t < NS * 7; t += 128) o[t] = 0.0f;
}

// --------------- fallback: fused sort + on-the-fly scan (no d_ws) -------------
__global__ __launch_bounds__(1024)
void nms_fused_kernel(const float* __restrict__ scores,
                      const float4* __restrict__ boxes,
                      const float* __restrict__ anchors,
                      float* __restrict__ out, int N, int NS) {
  __shared__ unsigned long long keys[4096];
  __shared__ int s_m;
  if (N > 4096) return;
  const int img = blockIdx.x;
  const int tid = threadIdx.x;
  const float* sc = scores + (size_t)img * N;
  const float4* bx = boxes + (size_t)img * N;
  if (tid == 0) s_m = 0;
  __syncthreads();
  int cnt = 0;
  for (int i = tid; i < N; i += blockDim.x) {
    float s = sc[i];
    keys[i] = ((unsigned long long)(~__float_as_uint(s)) << 32) | (unsigned)i;
    if (s > kScoreT) cnt++;
  }
  if (cnt) atomicAdd(&s_m, cnt);
  __syncthreads();
  for (int k = 2; k <= N; k <<= 1) {
    for (int j = k >> 1; j > 0; j >>= 1) {
      for (int i = tid; i < N; i += blockDim.x) {
        int ixj = i ^ j;
        if (ixj > i) {
          unsigned long long a = keys[i];
          unsigned long long b = keys[ixj];
          bool up = ((i & k) == 0);
          if (up ? (a > b) : (a < b)) { keys[i] = b; keys[ixj] = a; }
        }
      }
      __syncthreads();
    }
  }
  if (tid >= 64) return;
  const int lane = tid;
  const int m = s_m;
  const int nw = (m + 63) >> 6;
  const float* an = anchors + (size_t)img * N * 4;
  float* o = out + (size_t)img * NS * 7;
  unsigned long long remv = 0ull;
  int kept = 0;
  for (int i = 0; i < m && kept < NS; ++i) {
    unsigned long long rw = __shfl(remv, i >> 6, 64);
    if ((rw >> (i & 63)) & 1ull) continue;
    unsigned long long ki = keys[i];
    float4 bi = bx[(unsigned)ki];
    if (lane == 0) {
      unsigned idx = (unsigned)ki;
      float* row = o + kept * 7;
      row[0] = __uint_as_float(~(unsigned)(ki >> 32));
      row[1] = bi.x; row[2] = bi.y; row[3] = bi.z; row[4] = bi.w;
      row[5] = an[idx * 4 + 2];
      row[6] = an[idx * 4 + 3];
    }
    kept++;
    for (int w2 = i >> 6; w2 < nw; ++w2) {
      int j = (w2 << 6) | lane;
      bool sup = false;
      if (j > i && j < m) sup = iou_f(bi, bx[(unsigned)keys[j]]) > kIouT;
      unsigned long long bm = __ballot(sup);
      if (lane == w2) remv |= bm;
    }
  }
  for (int t = kept * 7 + lane; t < NS * 7; t += 64) o[t] = 0.0f;
}

extern "C" void kernel_launch(void* const* d_in, const int* in_sizes, int n_in,
                              void* d_out, int out_size, void* d_ws, size_t ws_size,
                              hipStream_t stream) {
  const float* scores = (const float*)d_in[0];
  const float4* boxes = (const float4*)d_in[1];
  const float* anchors = (const float*)d_in[2];
  float* out = (float*)d_out;
  const int B = 8;
  const int N = in_sizes[0] / B;      // 4096 boxes/image
  const int NS = out_size / (B * 7);  // 300 samples

  const size_t nTot = (size_t)B * (size_t)N;
  const size_t keysB = nTot * 8;
  const size_t sboxB = nTot * 16;
  const size_t mcntB = 256;
  const size_t maskB = nTot * (size_t)(N >> 6) * 8;
  const size_t need = keysB + sboxB + mcntB + maskB;

  if (ws_size >= need && (N % 256) == 0 && N >= 256 && NS <= kMaxKeep) {
    char* p = (char*)d_ws;
    unsigned long long* skeys = (unsigned long long*)p; p += keysB;
    float4* sboxes = (float4*)p;                         p += sboxB;
    int* Mcnt = (int*)p;                                 p += mcntB;
    unsigned long long* mask = (unsigned long long*)p;

    nms_count_kernel<<<B, 256, 0, stream>>>(scores, Mcnt, N);
    const int totalRows = B * N;
    const int rankBlocks = (int)(((long long)totalRows * 64 + 255) / 256);
    nms_rank_kernel<<<rankBlocks, 256, 0, stream>>>(scores, boxes, skeys,
                                                    sboxes, N);
    nms_mask_kernel<<<rankBlocks, 256, 0, stream>>>(sboxes, Mcnt, mask, N,
                                                    totalRows);
    nms_scan_kernel<<<B, 128, 0, stream>>>(skeys, sboxes, Mcnt, mask, anchors,
                                           out, N, NS);
  } else {
    nms_fused_kernel<<<B, 1024, 0, stream>>>(scores, boxes, anchors, out, N, NS);
  }
}

// Round 5
// 114.068 us; speedup vs baseline: 2.4297x; 1.0033x over previous
//
#include <hip/hip_runtime.h>

static constexpr float kIouT = 0.35f;
static constexpr float kScoreT = 0.5f;
static constexpr int kMaxNW = 36;     // pipelined scan supports m <= 36*64 = 2304
static constexpr int kStrideW = 37;   // padded LDS row stride (u64 words)
static constexpr int kDepth = 3;      // triple-buffered chunk pipeline
static constexpr int kProdWaves = 7;  // waves 1..7 produce, wave 0 consumes
static constexpr int kRowsPW = 10;    // ceil(64/7) rows per producer wave
static constexpr int kMaxKeep = 512;

// Bit-exact mirror of the reference IoU (no FMA contraction).
__device__ __forceinline__ float iou_f(const float4 a, const float4 b) {
  float areaA = __fmul_rn(a.z - a.x, a.w - a.y);
  float areaB = __fmul_rn(b.z - b.x, b.w - b.y);
  float iy1 = fmaxf(a.x, b.x);
  float ix1 = fmaxf(a.y, b.y);
  float iy2 = fminf(a.z, b.z);
  float ix2 = fminf(a.w, b.w);
  float dy = fmaxf(iy2 - iy1, 0.0f);
  float dx = fmaxf(ix2 - ix1, 0.0f);
  float inter = __fmul_rn(dy, dx);
  float uni = (areaA + areaB) - inter;
  return (uni > 0.0f) ? __fdiv_rn(inter, uni) : 0.0f;
}

// ---------------- kernel 0 — per-image valid count (no atomics) ---------------
__global__ __launch_bounds__(256)
void nms_count_kernel(const float* __restrict__ scores, int* __restrict__ Mcnt,
                      int N) {
  __shared__ int part[4];
  const int img = blockIdx.x, tid = threadIdx.x, lane = tid & 63, wv = tid >> 6;
  const float4* sc4 = (const float4*)(scores + (size_t)img * N);
  int c = 0;
  for (int q = tid; q < (N >> 2); q += 256) {
    float4 v = sc4[q];
    c += (v.x > kScoreT) + (v.y > kScoreT) + (v.z > kScoreT) + (v.w > kScoreT);
  }
#pragma unroll
  for (int off = 1; off < 64; off <<= 1) c += __shfl_xor(c, off, 64);
  if (lane == 0) part[wv] = c;
  __syncthreads();
  if (tid == 0) Mcnt[img] = part[0] + part[1] + part[2] + part[3];
}

// ---------------- kernel 1 — rank (counting) sort of the VALID prefix ---------
// One wave per row. For valid row i: rank = #{j: s_j > s_i} + #{j: s_j==s_i,
// j<i}. Invalid j (s<=0.5) sort after every valid i, so counting over ALL j
// gives the stable-descending position. Direct scatter; tail never read.
__global__ __launch_bounds__(256)
void nms_rank_kernel(const float* __restrict__ scores,
                     const float4* __restrict__ boxes,
                     unsigned long long* __restrict__ skeys,
                     float4* __restrict__ sboxes, int N) {
  const int wid = (int)(((unsigned)blockIdx.x * blockDim.x + threadIdx.x) >> 6);
  const int lane = threadIdx.x & 63;
  const int img = wid / N;
  const int row = wid - img * N;
  const float* sc = scores + (size_t)img * N;
  const float si = sc[row];
  if (!(si > kScoreT)) return;
  const float4* sc4 = (const float4*)sc;
  int cnt = 0;
  for (int q = lane; q < (N >> 2); q += 64) {   // coalesced, L1-resident
    const float4 v = sc4[q];
    const int j = q << 2;
    cnt += (v.x > si) + (v.y > si) + (v.z > si) + (v.w > si);
    if (v.x == si && j < row) cnt++;
    if (v.y == si && j + 1 < row) cnt++;
    if (v.z == si && j + 2 < row) cnt++;
    if (v.w == si && j + 3 < row) cnt++;
  }
#pragma unroll
  for (int off = 1; off < 64; off <<= 1) cnt += __shfl_xor(cnt, off, 64);
  if (lane == 0) {
    skeys[(size_t)img * N + cnt] =
        ((unsigned long long)(~__float_as_uint(si)) << 32) | (unsigned)row;
    sboxes[(size_t)img * N + cnt] = boxes[(size_t)img * N + row];
  }
}

// ------------- kernel 2 — pairwise IoU suppression masks -----------
__global__ __launch_bounds__(256)
void nms_mask_kernel(const float4* __restrict__ sboxes,
                     const int* __restrict__ Mcnt,
                     unsigned long long* __restrict__ mask,
                     int N, int totalRows) {
  const int wid = (int)(((unsigned)blockIdx.x * blockDim.x + threadIdx.x) >> 6);
  const int lane = threadIdx.x & 63;
  if (wid >= totalRows) return;
  const int img = wid / N;
  const int row = wid - img * N;
  const int m = Mcnt[img];
  if (row >= m) return;
  const float4* sb = sboxes + (size_t)img * N;
  const float4 bi = sb[row];
  const int nw = (m + 63) >> 6;
  unsigned long long* mrow = mask + (size_t)wid * (size_t)(N >> 6);
  for (int w = row >> 6; w < nw; ++w) {
    int j = (w << 6) | lane;
    bool sup = false;
    if (j > row && j < m) sup = iou_f(bi, sb[j]) > kIouT;
    unsigned long long bm = __ballot(sup);
    if (lane == 0) mrow[w] = bm;
  }
}

// ------------- kernel 3 — scan: 7 producer waves, 3-deep issue/commit pipe ----
// Period c: consumer (wave 0) scans chunk c from lbuf[c%3]; producer waves
// ds_write chunk c+1 (global loads issued in period c-1, so each load gets a
// full chunk-period of latency tolerance) then issue chunk c+2's loads into
// statically-indexed registers. Rows partitioned r == pw (mod 7); words
// w = c+lane (coalesced). Consumer chain per keep: ctz -> shfl(diag,b) -> or.
__global__ __launch_bounds__(512)
void nms_scan_kernel(const unsigned long long* __restrict__ skeys,
                     const float4* __restrict__ sboxes,
                     const int* __restrict__ Mcnt,
                     const unsigned long long* __restrict__ mask,
                     const float* __restrict__ anchors,
                     float* __restrict__ out, int N, int NS) {
  __shared__ unsigned long long lbuf[kDepth * 64 * kStrideW];  // ~55.5 KiB
  __shared__ int keptlist[kMaxKeep];
  __shared__ int s_done, s_kept;
  const int img = blockIdx.x;
  const int tid = threadIdx.x;
  const int lane = tid & 63;
  const int wv = tid >> 6;
  const int m = Mcnt[img];
  const int nw = (m + 63) >> 6;
  const int stride = N >> 6;  // mask row stride in u64
  const unsigned long long* mbase = mask + (size_t)img * (size_t)N * stride;
  const unsigned long long* kg = skeys + (size_t)img * N;
  const float4* sb = sboxes + (size_t)img * N;
  const float* an = anchors + (size_t)img * (size_t)N * 4;
  float* o = out + (size_t)img * NS * 7;
  if (tid == 0) { s_done = 0; s_kept = 0; }

  int kept = 0;
  unsigned long long remv = 0ull;

  if (m > 0 && nw <= kMaxNW) {
    const int pw = wv - 1;                 // producer wave id 0..6
    unsigned long long pv[kRowsPW];        // in-flight chunk (static idx only)
    auto issue = [&](int cc) {
      if (cc >= nw) return;
      const int base = cc << 6;
      const int rlim = min(m - base, 64);
      const int w = cc + lane;
      const bool wok = (w < nw);
#pragma unroll
      for (int k = 0; k < kRowsPW; ++k) {
        const int r = pw + k * kProdWaves;
        if (r < rlim && wok) pv[k] = mbase[(size_t)(base + r) * stride + w];
      }
    };
    auto commit = [&](int cc) {
      if (cc >= nw) return;
      const int base = cc << 6;
      const int rlim = min(m - base, 64);
      const int w = cc + lane;
      const bool wok = (w < nw);
      unsigned long long* dst = lbuf + (size_t)(cc % kDepth) * 64 * kStrideW;
#pragma unroll
      for (int k = 0; k < kRowsPW; ++k) {
        const int r = pw + k * kProdWaves;
        if (r < rlim && wok) dst[(size_t)r * kStrideW + w] = pv[k];
      }
    };
    if (wv != 0) {            // prologue: chunk 0 ready, chunk 1 in flight
      issue(0); commit(0);
      issue(1);
    }
    __syncthreads();
    for (int c = 0; c < nw; ++c) {
      if (wv == 0) {
        // ---- scan chunk c from lbuf[c%3] ----
        const unsigned long long* buf = lbuf + (size_t)(c % kDepth) * 64 * kStrideW;
        const unsigned long long diag = buf[(size_t)lane * kStrideW + c];
        unsigned long long local = __shfl(remv, c, 64);
        const int rem = m - (c << 6);
        unsigned long long avail = ~local;
        if (rem < 64) avail &= ((1ull << rem) - 1ull);
        while (avail != 0ull && kept < NS) {
          const int b = __builtin_ctzll(avail);
          if (lane == 0) keptlist[kept] = (c << 6) + b;
          kept++;
          const unsigned long long rc = __shfl(diag, b, 64);   // on-chain
          if (lane > c && lane < nw)
            remv |= buf[(size_t)b * kStrideW + lane];          // off-chain
          local |= rc;
          avail &= ~local;
          avail &= ~(1ull << b);
        }
        if (lane == 0 && kept >= NS) s_done = 1;
      } else {
        commit(c + 1);        // loads issued one period ago -> latency hidden
        issue(c + 2);
      }
      __syncthreads();
      if (s_done) break;
    }
  } else if (m > 0) {
    // safety fallback (m > 2304): wave 0 only, per-keep global mask-row loads.
    if (wv == 0) {
      for (int i = 0; i < m && kept < NS; ++i) {
        const unsigned long long rw = __shfl(remv, i >> 6, 64);
        if ((rw >> (i & 63)) & 1ull) continue;
        if (lane == 0) keptlist[kept] = i;
        kept++;
        const unsigned long long* mrow = mbase + (size_t)i * stride;
        if (lane >= (i >> 6) && lane < nw) remv |= mrow[lane];
      }
    }
  }

  if (wv == 0 && lane == 0) s_kept = kept;
  __syncthreads();
  const int K = s_kept;
  // parallel output: 512 threads over K kept rows
  for (int t = tid; t < K; t += 512) {
    const int i = keptlist[t];
    const unsigned long long ki = kg[i];
    const float4 bi = sb[i];
    const unsigned idx = (unsigned)ki;
    float* row = o + t * 7;
    row[0] = __uint_as_float(~(unsigned)(ki >> 32));
    row[1] = bi.x; row[2] = bi.y; row[3] = bi.z; row[4] = bi.w;
    row[5] = an[idx * 4 + 2];
    row[6] = an[idx * 4 + 3];
  }
  for (int t = K * 7 + tid; t < NS * 7; t += 512) o[t] = 0.0f;
}

// --------------- fallback: fused sort + on-the-fly scan (no d_ws) -------------
__global__ __launch_bounds__(1024)
void nms_fused_kernel(const float* __restrict__ scores,
                      const float4* __restrict__ boxes,
                      const float* __restrict__ anchors,
                      float* __restrict__ out, int N, int NS) {
  __shared__ unsigned long long keys[4096];
  __shared__ int s_m;
  if (N > 4096) return;
  const int img = blockIdx.x;
  const int tid = threadIdx.x;
  const float* sc = scores + (size_t)img * N;
  const float4* bx = boxes + (size_t)img * N;
  if (tid == 0) s_m = 0;
  __syncthreads();
  int cnt = 0;
  for (int i = tid; i < N; i += blockDim.x) {
    float s = sc[i];
    keys[i] = ((unsigned long long)(~__float_as_uint(s)) << 32) | (unsigned)i;
    if (s > kScoreT) cnt++;
  }
  if (cnt) atomicAdd(&s_m, cnt);
  __syncthreads();
  for (int k = 2; k <= N; k <<= 1) {
    for (int j = k >> 1; j > 0; j >>= 1) {
      for (int i = tid; i < N; i += blockDim.x) {
        int ixj = i ^ j;
        if (ixj > i) {
          unsigned long long a = keys[i];
          unsigned long long b = keys[ixj];
          bool up = ((i & k) == 0);
          if (up ? (a > b) : (a < b)) { keys[i] = b; keys[ixj] = a; }
        }
      }
      __syncthreads();
    }
  }
  if (tid >= 64) return;
  const int lane = tid;
  const int m = s_m;
  const int nw = (m + 63) >> 6;
  const float* an = anchors + (size_t)img * N * 4;
  float* o = out + (size_t)img * NS * 7;
  unsigned long long remv = 0ull;
  int kept = 0;
  for (int i = 0; i < m && kept < NS; ++i) {
    unsigned long long rw = __shfl(remv, i >> 6, 64);
    if ((rw >> (i & 63)) & 1ull) continue;
    unsigned long long ki = keys[i];
    float4 bi = bx[(unsigned)ki];
    if (lane == 0) {
      unsigned idx = (unsigned)ki;
      float* row = o + kept * 7;
      row[0] = __uint_as_float(~(unsigned)(ki >> 32));
      row[1] = bi.x; row[2] = bi.y; row[3] = bi.z; row[4] = bi.w;
      row[5] = an[idx * 4 + 2];
      row[6] = an[idx * 4 + 3];
    }
    kept++;
    for (int w2 = i >> 6; w2 < nw; ++w2) {
      int j = (w2 << 6) | lane;
      bool sup = false;
      if (j > i && j < m) sup = iou_f(bi, bx[(unsigned)keys[j]]) > kIouT;
      unsigned long long bm = __ballot(sup);
      if (lane == w2) remv |= bm;
    }
  }
  for (int t = kept * 7 + lane; t < NS * 7; t += 64) o[t] = 0.0f;
}

extern "C" void kernel_launch(void* const* d_in, const int* in_sizes, int n_in,
                              void* d_out, int out_size, void* d_ws, size_t ws_size,
                              hipStream_t stream) {
  const float* scores = (const float*)d_in[0];
  const float4* boxes = (const float4*)d_in[1];
  const float* anchors = (const float*)d_in[2];
  float* out = (float*)d_out;
  const int B = 8;
  const int N = in_sizes[0] / B;      // 4096 boxes/image
  const int NS = out_size / (B * 7);  // 300 samples

  const size_t nTot = (size_t)B * (size_t)N;
  const size_t keysB = nTot * 8;
  const size_t sboxB = nTot * 16;
  const size_t mcntB = 256;
  const size_t maskB = nTot * (size_t)(N >> 6) * 8;
  const size_t need = keysB + sboxB + mcntB + maskB;

  if (ws_size >= need && (N % 256) == 0 && N >= 256 && NS <= kMaxKeep) {
    char* p = (char*)d_ws;
    unsigned long long* skeys = (unsigned long long*)p; p += keysB;
    float4* sboxes = (float4*)p;                         p += sboxB;
    int* Mcnt = (int*)p;                                 p += mcntB;
    unsigned long long* mask = (unsigned long long*)p;

    nms_count_kernel<<<B, 256, 0, stream>>>(scores, Mcnt, N);
    const int totalRows = B * N;
    const int rankBlocks = (int)(((long long)totalRows * 64 + 255) / 256);
    nms_rank_kernel<<<rankBlocks, 256, 0, stream>>>(scores, boxes, skeys,
                                                    sboxes, N);
    nms_mask_kernel<<<rankBlocks, 256, 0, stream>>>(sboxes, Mcnt, mask, N,
                                                    totalRows);
    nms_scan_kernel<<<B, 512, 0, stream>>>(skeys, sboxes, Mcnt, mask, anchors,
                                           out, N, NS);
  } else {
    nms_fused_kernel<<<B, 1024, 0, stream>>>(scores, boxes, anchors, out, N, NS);
  }
}

// Round 6
// 108.215 us; speedup vs baseline: 2.5611x; 1.0541x over previous
//
#include <hip/hip_runtime.h>

static constexpr float kIouT = 0.35f;
static constexpr float kScoreT = 0.5f;
static constexpr int kMaxKeep = 512;

// Bit-exact mirror of the reference IoU (no FMA contraction).
__device__ __forceinline__ float iou_f(const float4 a, const float4 b) {
  float areaA = __fmul_rn(a.z - a.x, a.w - a.y);
  float areaB = __fmul_rn(b.z - b.x, b.w - b.y);
  float iy1 = fmaxf(a.x, b.x);
  float ix1 = fmaxf(a.y, b.y);
  float iy2 = fminf(a.z, b.z);
  float ix2 = fminf(a.w, b.w);
  float dy = fmaxf(iy2 - iy1, 0.0f);
  float dx = fmaxf(ix2 - ix1, 0.0f);
  float inter = __fmul_rn(dy, dx);
  float uni = (areaA + areaB) - inter;
  return (uni > 0.0f) ? __fdiv_rn(inter, uni) : 0.0f;
}

// 64-bit cross-lane pull with UNIFORM lane index: v_readlane (VALU, ~5cy)
// instead of ds_bpermute (~100+cy) — the round-4 scan bottleneck.
__device__ __forceinline__ unsigned long long rdlane64(unsigned long long v,
                                                       int l) {
  unsigned lo = (unsigned)__builtin_amdgcn_readlane((int)(unsigned)v, l);
  unsigned hi = (unsigned)__builtin_amdgcn_readlane((int)(unsigned)(v >> 32), l);
  return ((unsigned long long)hi << 32) | lo;
}

// ------- kernel 1 — rank (counting) sort of the VALID prefix (+count fold) ----
// Blocks [0, rankBlocks): one wave per row. For valid row i: rank =
// #{j: s_j > s_i} + #{j: s_j==s_i, j<i}. Invalid j (s<=0.5) sort after every
// valid i, so counting over ALL j gives the stable-descending position.
// Blocks [rankBlocks, rankBlocks+B): per-image valid count -> Mcnt.
__global__ __launch_bounds__(256)
void nms_rank_kernel(const float* __restrict__ scores,
                     const float4* __restrict__ boxes,
                     unsigned long long* __restrict__ skeys,
                     float4* __restrict__ sboxes,
                     int* __restrict__ Mcnt, int N, int rankBlocks) {
  const int tid = threadIdx.x;
  const int lane = tid & 63;
  if ((int)blockIdx.x >= rankBlocks) {   // ---- count mode ----
    __shared__ int part[4];
    const int img = blockIdx.x - rankBlocks;
    const int wv = tid >> 6;
    const float4* sc4 = (const float4*)(scores + (size_t)img * N);
    int c = 0;
    for (int q = tid; q < (N >> 2); q += 256) {
      float4 v = sc4[q];
      c += (v.x > kScoreT) + (v.y > kScoreT) + (v.z > kScoreT) + (v.w > kScoreT);
    }
#pragma unroll
    for (int off = 1; off < 64; off <<= 1) c += __shfl_xor(c, off, 64);
    if (lane == 0) part[wv] = c;
    __syncthreads();
    if (tid == 0) Mcnt[img] = part[0] + part[1] + part[2] + part[3];
    return;
  }
  // ---- rank mode ----
  const int wid = (int)(((unsigned)blockIdx.x * blockDim.x + tid) >> 6);
  const int img = wid / N;
  const int row = wid - img * N;
  const float* sc = scores + (size_t)img * N;
  const float si = sc[row];
  if (!(si > kScoreT)) return;
  const float4* sc4 = (const float4*)sc;
  int cnt = 0;
  for (int q = lane; q < (N >> 2); q += 64) {   // coalesced, L1-resident
    const float4 v = sc4[q];
    const int j = q << 2;
    cnt += (v.x > si) + (v.y > si) + (v.z > si) + (v.w > si);
    if (v.x == si && j < row) cnt++;
    if (v.y == si && j + 1 < row) cnt++;
    if (v.z == si && j + 2 < row) cnt++;
    if (v.w == si && j + 3 < row) cnt++;
  }
#pragma unroll
  for (int off = 1; off < 64; off <<= 1) cnt += __shfl_xor(cnt, off, 64);
  if (lane == 0) {
    skeys[(size_t)img * N + cnt] =
        ((unsigned long long)(~__float_as_uint(si)) << 32) | (unsigned)row;
    sboxes[(size_t)img * N + cnt] = boxes[(size_t)img * N + row];
  }
}

// ------------- kernel 2 — pairwise IoU suppression masks -----------
__global__ __launch_bounds__(256)
void nms_mask_kernel(const float4* __restrict__ sboxes,
                     const int* __restrict__ Mcnt,
                     unsigned long long* __restrict__ mask,
                     int N, int totalRows) {
  const int wid = (int)(((unsigned)blockIdx.x * blockDim.x + threadIdx.x) >> 6);
  const int lane = threadIdx.x & 63;
  if (wid >= totalRows) return;
  const int img = wid / N;
  const int row = wid - img * N;
  const int m = Mcnt[img];
  if (row >= m) return;
  const float4* sb = sboxes + (size_t)img * N;
  const float4 bi = sb[row];
  const int nw = (m + 63) >> 6;
  unsigned long long* mrow = mask + (size_t)wid * (size_t)(N >> 6);
  for (int w = row >> 6; w < nw; ++w) {
    int j = (w << 6) | lane;
    bool sup = false;
    if (j > row && j < m) sup = iou_f(bi, sb[j]) > kIouT;
    unsigned long long bm = __ballot(sup);
    if (lane == 0) mrow[w] = bm;
  }
}

// ------------- kernel 3 — single-wave scalar scan (readlane chain) -----------
// remv: lane l owns suppression word l (register). Per chunk c:
//   local = rdlane64(remv, c); serial keep loop entirely in SALU/readlane:
//   b = ctz(avail) -> rc = rdlane64(dg0, b) -> local|=rc -> avail. ~30cy/keep.
// Diag words (within-chunk suppression, word c of rows c*64+lane) prefetched
// 3 chunks ahead in a register shift pipeline (dg0<-dg1<-dg2<-load).
// Kept rows' full mask words are OR'd into remv at chunk end in batches of 8
// independent global loads (one latency per keep-bearing chunk, off-chain).
// No barriers, no producer waves. Supports m <= 4096 (lane-owned words);
// the benchmarked shape has m <= N = 4096 always.
__global__ __launch_bounds__(64)
void nms_scan_kernel(const unsigned long long* __restrict__ skeys,
                     const float4* __restrict__ sboxes,
                     const int* __restrict__ Mcnt,
                     const unsigned long long* __restrict__ mask,
                     const float* __restrict__ anchors,
                     float* __restrict__ out, int N, int NS) {
  __shared__ int keptlist[kMaxKeep];
  const int img = blockIdx.x;
  const int lane = threadIdx.x;
  int m = Mcnt[img];
  if (m > N) m = N;                    // clamp (defensive; never hit here)
  const int nw = (m + 63) >> 6;        // <= 64 since m <= 4096
  const int stride = N >> 6;
  const unsigned long long* mbase = mask + (size_t)img * (size_t)N * stride;
  const unsigned long long* kg = skeys + (size_t)img * N;
  const float4* sb = sboxes + (size_t)img * N;
  const float* an = anchors + (size_t)img * (size_t)N * 4;
  float* o = out + (size_t)img * NS * 7;

  int kept = 0;
  unsigned long long remv = 0ull;

  if (m > 0) {
    // diag prefetch: chunk cc's diag word for this lane = row cc*64+lane,
    // word cc. Rows >= m in the last chunk read garbage that is masked off
    // by the lim mask and never readlane'd (address stays in-bounds).
    auto dgload = [&](int cc) -> unsigned long long {
      return (cc < nw) ? mbase[(size_t)((cc << 6) + lane) * stride + cc] : 0ull;
    };
    unsigned long long dg0 = dgload(0);
    unsigned long long dg1 = dgload(1);
    unsigned long long dg2 = dgload(2);

    for (int c = 0; c < nw && kept < NS; ++c) {
      const int cb = c << 6;
      unsigned long long local = rdlane64(remv, c);
      const int rem = m - cb;
      unsigned long long avail = ~local;
      if (rem < 64) avail &= (1ull << rem) - 1ull;
      unsigned long long keptbits = 0ull;
      // ---- serial greedy loop: pure scalar + readlane, ~30cy/keep ----
      while (avail != 0ull && kept < NS) {
        const int b = (int)__builtin_ctzll(avail);
        if (lane == 0) keptlist[kept] = cb + b;
        kept++;
        keptbits |= 1ull << b;
        const unsigned long long rc = rdlane64(dg0, b);  // word c of row cb+b
        local |= rc;
        avail &= ~local;
        avail &= ~(1ull << b);
      }
      // ---- rotate diag pipeline (issue before the delta-wait) ----
      dg0 = dg1; dg1 = dg2; dg2 = dgload(c + 3);
      // ---- delta: OR kept rows' mask words into lane-owned remv ----
      const bool lok = (lane > c) && (lane < nw);
      while (keptbits != 0ull) {
        unsigned long long t[8];
        int bs[8];
#pragma unroll
        for (int k = 0; k < 8; ++k) {
          if (keptbits != 0ull) {
            bs[k] = (int)__builtin_ctzll(keptbits);
            keptbits &= keptbits - 1ull;
          } else {
            bs[k] = -1;
          }
        }
#pragma unroll
        for (int k = 0; k < 8; ++k)       // 8 independent loads in flight
          t[k] = (bs[k] >= 0 && lok)
                     ? mbase[(size_t)(cb + bs[k]) * stride + lane]
                     : 0ull;
#pragma unroll
        for (int k = 0; k < 8; ++k)
          if (bs[k] >= 0) remv |= t[k];
      }
    }
  }

  __syncthreads();  // single wave: just drains LDS writes of keptlist
  // parallel output over the wave
  for (int t = lane; t < kept; t += 64) {
    const int i = keptlist[t];
    const unsigned long long ki = kg[i];
    const float4 bi = sb[i];
    const unsigned idx = (unsigned)ki;
    float* row = o + t * 7;
    row[0] = __uint_as_float(~(unsigned)(ki >> 32));
    row[1] = bi.x; row[2] = bi.y; row[3] = bi.z; row[4] = bi.w;
    row[5] = an[idx * 4 + 2];
    row[6] = an[idx * 4 + 3];
  }
  for (int t = kept * 7 + lane; t < NS * 7; t += 64) o[t] = 0.0f;
}

// --------------- fallback: fused sort + on-the-fly scan (no d_ws) -------------
__global__ __launch_bounds__(1024)
void nms_fused_kernel(const float* __restrict__ scores,
                      const float4* __restrict__ boxes,
                      const float* __restrict__ anchors,
                      float* __restrict__ out, int N, int NS) {
  __shared__ unsigned long long keys[4096];
  __shared__ int s_m;
  if (N > 4096) return;
  const int img = blockIdx.x;
  const int tid = threadIdx.x;
  const float* sc = scores + (size_t)img * N;
  const float4* bx = boxes + (size_t)img * N;
  if (tid == 0) s_m = 0;
  __syncthreads();
  int cnt = 0;
  for (int i = tid; i < N; i += blockDim.x) {
    float s = sc[i];
    keys[i] = ((unsigned long long)(~__float_as_uint(s)) << 32) | (unsigned)i;
    if (s > kScoreT) cnt++;
  }
  if (cnt) atomicAdd(&s_m, cnt);
  __syncthreads();
  for (int k = 2; k <= N; k <<= 1) {
    for (int j = k >> 1; j > 0; j >>= 1) {
      for (int i = tid; i < N; i += blockDim.x) {
        int ixj = i ^ j;
        if (ixj > i) {
          unsigned long long a = keys[i];
          unsigned long long b = keys[ixj];
          bool up = ((i & k) == 0);
          if (up ? (a > b) : (a < b)) { keys[i] = b; keys[ixj] = a; }
        }
      }
      __syncthreads();
    }
  }
  if (tid >= 64) return;
  const int lane = tid;
  const int m = s_m;
  const int nw = (m + 63) >> 6;
  const float* an = anchors + (size_t)img * N * 4;
  float* o = out + (size_t)img * NS * 7;
  unsigned long long remv = 0ull;
  int kept = 0;
  for (int i = 0; i < m && kept < NS; ++i) {
    unsigned long long rw = __shfl(remv, i >> 6, 64);
    if ((rw >> (i & 63)) & 1ull) continue;
    unsigned long long ki = keys[i];
    float4 bi = bx[(unsigned)ki];
    if (lane == 0) {
      unsigned idx = (unsigned)ki;
      float* row = o + kept * 7;
      row[0] = __uint_as_float(~(unsigned)(ki >> 32));
      row[1] = bi.x; row[2] = bi.y; row[3] = bi.z; row[4] = bi.w;
      row[5] = an[idx * 4 + 2];
      row[6] = an[idx * 4 + 3];
    }
    kept++;
    for (int w2 = i >> 6; w2 < nw; ++w2) {
      int j = (w2 << 6) | lane;
      bool sup = false;
      if (j > i && j < m) sup = iou_f(bi, bx[(unsigned)keys[j]]) > kIouT;
      unsigned long long bm = __ballot(sup);
      if (lane == w2) remv |= bm;
    }
  }
  for (int t = kept * 7 + lane; t < NS * 7; t += 64) o[t] = 0.0f;
}

extern "C" void kernel_launch(void* const* d_in, const int* in_sizes, int n_in,
                              void* d_out, int out_size, void* d_ws, size_t ws_size,
                              hipStream_t stream) {
  const float* scores = (const float*)d_in[0];
  const float4* boxes = (const float4*)d_in[1];
  const float* anchors = (const float*)d_in[2];
  float* out = (float*)d_out;
  const int B = 8;
  const int N = in_sizes[0] / B;      // 4096 boxes/image
  const int NS = out_size / (B * 7);  // 300 samples

  const size_t nTot = (size_t)B * (size_t)N;
  const size_t keysB = nTot * 8;
  const size_t sboxB = nTot * 16;
  const size_t mcntB = 256;
  const size_t maskB = nTot * (size_t)(N >> 6) * 8;
  const size_t need = keysB + sboxB + mcntB + maskB;

  if (ws_size >= need && (N % 256) == 0 && N >= 256 && N <= 4096 &&
      NS <= kMaxKeep) {
    char* p = (char*)d_ws;
    unsigned long long* skeys = (unsigned long long*)p; p += keysB;
    float4* sboxes = (float4*)p;                         p += sboxB;
    int* Mcnt = (int*)p;                                 p += mcntB;
    unsigned long long* mask = (unsigned long long*)p;

    const int totalRows = B * N;
    const int rankBlocks = totalRows / 4;  // 256 thr = 4 waves per block
    nms_rank_kernel<<<rankBlocks + B, 256, 0, stream>>>(scores, boxes, skeys,
                                                        sboxes, Mcnt, N,
                                                        rankBlocks);
    nms_mask_kernel<<<rankBlocks, 256, 0, stream>>>(sboxes, Mcnt, mask, N,
                                                    totalRows);
    nms_scan_kernel<<<B, 64, 0, stream>>>(skeys, sboxes, Mcnt, mask, anchors,
                                          out, N, NS);
  } else {
    nms_fused_kernel<<<B, 1024, 0, stream>>>(scores, boxes, anchors, out, N, NS);
  }
}